// Round 11
// baseline (46.093 us; speedup 1.0000x reference)
//
#include <hip/hip_runtime.h>
#include <hip/hip_bf16.h>

#define B_   4
#define C_   128
#define H_   64
#define W_   64
#define HW_  4096
#define KW_  7
#define PAD_ 3
#define G_   8
#define CPG_ 16

#define CPAD 136   // f16 elems per LDS row in proj; row stride 272 B

// attn LDS geometry
#define TS    16
#define HALO  22
#define NHP   (HALO*HALO)
#define LP    24          // ushorts per pixel (48 B): balanced banks, 16B-aligned

typedef _Float16 f16x8 __attribute__((ext_vector_type(8)));
typedef _Float16 h2    __attribute__((ext_vector_type(2)));
typedef float    f32x4 __attribute__((ext_vector_type(4)));

static __device__ __forceinline__ unsigned short f2h(float f) {
    _Float16 h = (_Float16)f;
    union { _Float16 h; unsigned short u; } cv; cv.h = h;
    return cv.u;
}

#if defined(__has_builtin)
#if __has_builtin(__builtin_amdgcn_fdot2)
#define HAVE_FDOT2 1
#endif
#endif

// ---------------------------------------------------------------------------
// Kernel A: fp16-MFMA 1x1 conv projections (VERBATIM round-10).
// grid: (64 p-tiles, B, 3), block 256 (4 waves).
// ---------------------------------------------------------------------------
__global__ __launch_bounds__(256) void proj_mfma(
    const float* __restrict__ x,
    const float* __restrict__ Wq,
    const float* __restrict__ Wk,
    const float* __restrict__ Wv,
    unsigned short* __restrict__ qkv16)
{
    const int ptile = blockIdx.x;   // 0..63
    const int b     = blockIdx.y;
    const int m     = blockIdx.z;
    const float* Wm = (m == 0) ? Wq : ((m == 1) ? Wk : Wv);
    const float* xb = x + (size_t)b * C_ * HW_;
    unsigned short* y = qkv16 + ((size_t)(m * B_ + b)) * HW_ * C_;
    const int p0  = ptile * 64;
    const int tid = threadIdx.x;

    __shared__ unsigned short wls[128 * CPAD];  // [o][c] f16
    __shared__ unsigned short xls[64 * CPAD];   // [p][c] f16 (transposed X)

    #pragma unroll
    for (int it = 0; it < 16; ++it) {
        const int idx = tid + it * 256;
        const int o   = idx >> 5;
        const int c4  = (idx & 31) * 4;
        const float4 w4 = *(const float4*)(Wm + (size_t)o * C_ + c4);
        ushort4 hh;
        hh.x = f2h(w4.x); hh.y = f2h(w4.y); hh.z = f2h(w4.z); hh.w = f2h(w4.w);
        *(ushort4*)(&wls[o * CPAD + c4]) = hh;
    }
    #pragma unroll
    for (int it = 0; it < 2; ++it) {
        const int idx = tid + it * 256;
        const int pq  = (idx & 15) * 4;
        const int cq  = (idx >> 4) * 4;
        const float* xp = xb + (size_t)cq * HW_ + p0 + pq;
        const float4 r0 = *(const float4*)(xp);
        const float4 r1 = *(const float4*)(xp + HW_);
        const float4 r2 = *(const float4*)(xp + 2 * HW_);
        const float4 r3 = *(const float4*)(xp + 3 * HW_);
        ushort4 hh;
        hh.x = f2h(r0.x); hh.y = f2h(r1.x); hh.z = f2h(r2.x); hh.w = f2h(r3.x);
        *(ushort4*)(&xls[(pq + 0) * CPAD + cq]) = hh;
        hh.x = f2h(r0.y); hh.y = f2h(r1.y); hh.z = f2h(r2.y); hh.w = f2h(r3.y);
        *(ushort4*)(&xls[(pq + 1) * CPAD + cq]) = hh;
        hh.x = f2h(r0.z); hh.y = f2h(r1.z); hh.z = f2h(r2.z); hh.w = f2h(r3.z);
        *(ushort4*)(&xls[(pq + 2) * CPAD + cq]) = hh;
        hh.x = f2h(r0.w); hh.y = f2h(r1.w); hh.z = f2h(r2.w); hh.w = f2h(r3.w);
        *(ushort4*)(&xls[(pq + 3) * CPAD + cq]) = hh;
    }
    __syncthreads();

    const int wv   = tid >> 6;
    const int lane = tid & 63;
    const int row  = lane & 15;
    const int kq   = lane >> 4;

    f32x4 acc[8];
    #pragma unroll
    for (int ot = 0; ot < 8; ++ot)
        acc[ot] = (f32x4){0.f, 0.f, 0.f, 0.f};

    #pragma unroll
    for (int ks = 0; ks < 4; ++ks) {
        const int cb = ks * 32 + kq * 8;
        const f16x8 bfrag = *(const f16x8*)(&xls[(wv * 16 + row) * CPAD + cb]);
        #pragma unroll
        for (int ot = 0; ot < 8; ++ot) {
            const f16x8 afrag = *(const f16x8*)(&wls[(ot * 16 + row) * CPAD + cb]);
            acc[ot] = __builtin_amdgcn_mfma_f32_16x16x32_f16(afrag, bfrag, acc[ot], 0, 0, 0);
        }
    }

    const int p = p0 + wv * 16 + row;
    #pragma unroll
    for (int ot = 0; ot < 8; ++ot) {
        ushort4 hh;
        hh.x = f2h(acc[ot][0]); hh.y = f2h(acc[ot][1]);
        hh.z = f2h(acc[ot][2]); hh.w = f2h(acc[ot][3]);
        *(ushort4*)(y + ((size_t)ot * HW_ + p) * CPG_ + kq * 4) = hh;
    }
}

// ---------------------------------------------------------------------------
// Kernel B: grouped 7x7 local attention, vertical 2-px/thread.
// Block 128 threads = one 16x16 tile (thread = (row-pair, col)).
// Row-iteration shares each K/V row-vector load between the two pixels:
// LDS reads/px 196 -> 112.
// grid: (16 tiles, G, B), block 128.
// ---------------------------------------------------------------------------
__global__ __launch_bounds__(128) void attn_kernel(
    const unsigned short* __restrict__ qkv16,
    const float* __restrict__ rel_h,   // [64][7]
    const float* __restrict__ rel_w,   // [64][7]
    float* __restrict__ out)           // [B][128][64][64]
{
    const int tile = blockIdx.x;
    const int g    = blockIdx.y;
    const int b    = blockIdx.z;
    const int h0   = (tile >> 2) * TS;
    const int w0   = (tile & 3) * TS;
    const int c0   = g * CPG_;

    __shared__ unsigned short kls[NHP * LP];
    __shared__ unsigned short vls[NHP * LP];

    const size_t gplane = (size_t)HW_ * CPG_;
    const size_t mplane = (size_t)B_ * G_ * gplane;
    const unsigned short* qb = qkv16              + ((size_t)b * G_ + g) * gplane;
    const unsigned short* kb = qkv16 + mplane     + ((size_t)b * G_ + g) * gplane;
    const unsigned short* vb = qkv16 + 2 * mplane + ((size_t)b * G_ + g) * gplane;

    const int tid = threadIdx.x;
    const int pw  = tid & 15;
    const int php = tid >> 4;          // 0..7 -> rows 2php, 2php+1
    const int row0 = 2 * php;
    const int pix0 = (h0 + row0) * W_ + (w0 + pw);
    const int pix1 = pix0 + W_;

    // q fragments for both pixels (issued before staging -> overlap)
    const f16x8 q0a = *(const f16x8*)(qb + (size_t)pix0 * CPG_);
    const f16x8 q0b = *(const f16x8*)(qb + (size_t)pix0 * CPG_ + 8);
    const f16x8 q1a = *(const f16x8*)(qb + (size_t)pix1 * CPG_);
    const f16x8 q1b = *(const f16x8*)(qb + (size_t)pix1 * CPG_ + 8);

    // stage K and V halo: 1936 x 16B chunks, zero-fill OOB
    #pragma unroll
    for (int it = 0; it < 16; ++it) {
        const int idx = tid + it * 128;
        if (idx < 2 * NHP * 2) {
            const int arr  = (idx >= NHP * 2) ? 1 : 0;
            const int r    = idx - arr * NHP * 2;
            const int lp   = r >> 1;
            const int half = r & 1;
            const int hy   = h0 + lp / HALO - PAD_;
            const int hx   = w0 + lp % HALO - PAD_;
            f16x8 val = (f16x8)(_Float16)0.f;
            if ((unsigned)hy < (unsigned)H_ && (unsigned)hx < (unsigned)W_) {
                const unsigned short* src = (arr ? vb : kb)
                    + (size_t)(hy * W_ + hx) * CPG_ + half * 8;
                val = *(const f16x8*)src;
            }
            unsigned short* dst = (arr ? vls : kls) + lp * LP + half * 8;
            *(f16x8*)dst = val;
        }
    }

    // rel components (fp32) for both pixels
    const bool useH = (g < 4);
    const float* rp = useH ? (rel_h + c0 * KW_) : (rel_w + (c0 - 64) * KW_);
    float rel0[KW_], rel1[KW_];
    {
        float qv0[CPG_], qv1[CPG_];
        #pragma unroll
        for (int c = 0; c < 8; ++c) {
            qv0[c] = (float)q0a[c]; qv0[8 + c] = (float)q0b[c];
            qv1[c] = (float)q1a[c]; qv1[8 + c] = (float)q1b[c];
        }
        #pragma unroll
        for (int t = 0; t < KW_; ++t) {
            float r0 = 0.f, r1 = 0.f;
            #pragma unroll
            for (int c = 0; c < CPG_; ++c) {
                const float w = rp[c * KW_ + t];
                r0 += qv0[c] * w;
                r1 += qv1[c] * w;
            }
            rel0[t] = r0; rel1[t] = r1;
        }
    }

    __syncthreads();

    // scores: init with rel, accumulate K dots row by row (A half then B half)
    float s0[KW_ * KW_], s1[KW_ * KW_];
    #pragma unroll
    for (int i = 0; i < KW_; ++i)
        #pragma unroll
        for (int j = 0; j < KW_; ++j) {
            s0[i * KW_ + j] = useH ? rel0[i] : rel0[j];
            s1[i * KW_ + j] = useH ? rel1[i] : rel1[j];
        }

    #pragma unroll
    for (int r = 0; r < 8; ++r) {
        const int base = ((row0 + r) * HALO + pw) * LP;
        // A half (ch 0-7)
        {
            f16x8 ka[KW_];
            #pragma unroll
            for (int t = 0; t < KW_; ++t)
                ka[t] = *(const f16x8*)(&kls[base + t * LP]);
            if (r < 7) {
                #pragma unroll
                for (int j = 0; j < KW_; ++j) {
                    float sc = s0[r * KW_ + j];
#ifdef HAVE_FDOT2
                    #pragma unroll
                    for (int t = 0; t < 4; ++t)
                        sc = __builtin_amdgcn_fdot2((h2){q0a[2*t], q0a[2*t+1]},
                                                    (h2){ka[j][2*t], ka[j][2*t+1]}, sc, false);
#else
                    #pragma unroll
                    for (int c = 0; c < 8; ++c) sc += (float)q0a[c] * (float)ka[j][c];
#endif
                    s0[r * KW_ + j] = sc;
                }
            }
            if (r >= 1) {
                #pragma unroll
                for (int j = 0; j < KW_; ++j) {
                    float sc = s1[(r - 1) * KW_ + j];
#ifdef HAVE_FDOT2
                    #pragma unroll
                    for (int t = 0; t < 4; ++t)
                        sc = __builtin_amdgcn_fdot2((h2){q1a[2*t], q1a[2*t+1]},
                                                    (h2){ka[j][2*t], ka[j][2*t+1]}, sc, false);
#else
                    #pragma unroll
                    for (int c = 0; c < 8; ++c) sc += (float)q1a[c] * (float)ka[j][c];
#endif
                    s1[(r - 1) * KW_ + j] = sc;
                }
            }
        }
        // B half (ch 8-15)
        {
            f16x8 kb2[KW_];
            #pragma unroll
            for (int t = 0; t < KW_; ++t)
                kb2[t] = *(const f16x8*)(&kls[base + t * LP + 8]);
            if (r < 7) {
                #pragma unroll
                for (int j = 0; j < KW_; ++j) {
                    float sc = s0[r * KW_ + j];
#ifdef HAVE_FDOT2
                    #pragma unroll
                    for (int t = 0; t < 4; ++t)
                        sc = __builtin_amdgcn_fdot2((h2){q0b[2*t], q0b[2*t+1]},
                                                    (h2){kb2[j][2*t], kb2[j][2*t+1]}, sc, false);
#else
                    #pragma unroll
                    for (int c = 0; c < 8; ++c) sc += (float)q0b[c] * (float)kb2[j][c];
#endif
                    s0[r * KW_ + j] = sc;
                }
            }
            if (r >= 1) {
                #pragma unroll
                for (int j = 0; j < KW_; ++j) {
                    float sc = s1[(r - 1) * KW_ + j];
#ifdef HAVE_FDOT2
                    #pragma unroll
                    for (int t = 0; t < 4; ++t)
                        sc = __builtin_amdgcn_fdot2((h2){q1b[2*t], q1b[2*t+1]},
                                                    (h2){kb2[j][2*t], kb2[j][2*t+1]}, sc, false);
#else
                    #pragma unroll
                    for (int c = 0; c < 8; ++c) sc += (float)q1b[c] * (float)kb2[j][c];
#endif
                    s1[(r - 1) * KW_ + j] = sc;
                }
            }
        }
    }

    // softmax for both pixels
    float smax0 = -1e30f, smax1 = -1e30f;
    #pragma unroll
    for (int n = 0; n < KW_ * KW_; ++n) {
        smax0 = fmaxf(smax0, s0[n]);
        smax1 = fmaxf(smax1, s1[n]);
    }
    float den0 = 0.f, den1 = 0.f;
    #pragma unroll
    for (int n = 0; n < KW_ * KW_; ++n) {
        s0[n] = __expf(s0[n] - smax0); den0 += s0[n];
        s1[n] = __expf(s1[n] - smax1); den1 += s1[n];
    }
    const float rd0 = 1.f / den0;
    const float rd1 = 1.f / den1;

    // PV: row-shared V loads
    float acc0[CPG_], acc1[CPG_];
    #pragma unroll
    for (int c = 0; c < CPG_; ++c) { acc0[c] = 0.f; acc1[c] = 0.f; }

    #pragma unroll
    for (int r = 0; r < 8; ++r) {
        const int base = ((row0 + r) * HALO + pw) * LP;
        f16x8 va[KW_], vb2[KW_];
        #pragma unroll
        for (int t = 0; t < KW_; ++t) {
            va[t]  = *(const f16x8*)(&vls[base + t * LP]);
            vb2[t] = *(const f16x8*)(&vls[base + t * LP + 8]);
        }
        if (r < 7) {
            #pragma unroll
            for (int j = 0; j < KW_; ++j) {
                const float a = s0[r * KW_ + j];
                #pragma unroll
                for (int c = 0; c < 8; ++c) {
                    acc0[c]     += a * (float)va[j][c];
                    acc0[8 + c] += a * (float)vb2[j][c];
                }
            }
        }
        if (r >= 1) {
            #pragma unroll
            for (int j = 0; j < KW_; ++j) {
                const float a = s1[(r - 1) * KW_ + j];
                #pragma unroll
                for (int c = 0; c < 8; ++c) {
                    acc1[c]     += a * (float)va[j][c];
                    acc1[8 + c] += a * (float)vb2[j][c];
                }
            }
        }
    }

    float* ob = out + ((size_t)b * C_ + c0) * HW_;
    #pragma unroll
    for (int c = 0; c < CPG_; ++c) {
        ob[(size_t)c * HW_ + pix0] = acc0[c] * rd0;
        ob[(size_t)c * HW_ + pix1] = acc1[c] * rd1;
    }
}

// ---------------------------------------------------------------------------
extern "C" void kernel_launch(void* const* d_in, const int* in_sizes, int n_in,
                              void* d_out, int out_size, void* d_ws, size_t ws_size,
                              hipStream_t stream) {
    const float* x     = (const float*)d_in[0];
    const float* Wq    = (const float*)d_in[1];
    const float* Wk    = (const float*)d_in[2];
    const float* Wv    = (const float*)d_in[3];
    const float* rel_h = (const float*)d_in[4];
    const float* rel_w = (const float*)d_in[5];
    unsigned short* ws = (unsigned short*)d_ws;  // fp16 qkv [3][B][G][4096][16] = 12 MB
    float* out = (float*)d_out;

    dim3 gA(HW_ / 64, B_, 3);
    proj_mfma<<<gA, 256, 0, stream>>>(x, Wq, Wk, Wv, ws);

    dim3 gB(16, G_, B_);
    attn_kernel<<<gB, 128, 0, stream>>>(ws, rel_h, rel_w, out);
}

// Round 12
// 40.784 us; speedup vs baseline: 1.1302x; 1.1302x over previous
//
#include <hip/hip_runtime.h>
#include <hip/hip_bf16.h>

#define B_   4
#define C_   128
#define H_   64
#define W_   64
#define HW_  4096
#define KW_  7
#define PAD_ 3
#define G_   8
#define CPG_ 16

#define CPAD 136   // f16 elems per LDS row in proj; row stride 272 B

// attn geometry
#define TS     16
#define HALOY  22
#define KWP    24      // kls per-pixel pitch (ushorts, 48 B, 16B-aligned)
#define VWP    40      // vls per-(y,c) pitch (ushorts, 80 B, 16B-aligned)
#define IPITCH 80      // v_img x pitch (f16)
#define IROWS  72      // v_img rows

typedef _Float16 f16x4 __attribute__((ext_vector_type(4)));
typedef _Float16 f16x8 __attribute__((ext_vector_type(8)));
typedef float    f32x4 __attribute__((ext_vector_type(4)));

static __device__ __forceinline__ unsigned short f2h(float f) {
    _Float16 h = (_Float16)f;
    union { _Float16 h; unsigned short u; } cv; cv.h = h;
    return cv.u;
}
static __device__ __forceinline__ float andf(float x, unsigned m) {
    return __uint_as_float(__float_as_uint(x) & m);
}

// ---------------------------------------------------------------------------
// Kernel A: fp16-MFMA 1x1 conv projections (R10 core).
// q,k -> pixel-major qkv16[m][b][g][pix][16]; v -> padded channel-major image
// v_img[b][c][72][80] (interior at +3; borders zeroed by all proj blocks).
// grid: (64 p-tiles, B, 3), block 256 (4 waves).
// ---------------------------------------------------------------------------
__global__ __launch_bounds__(256) void proj_mfma(
    const float* __restrict__ x,
    const float* __restrict__ Wq,
    const float* __restrict__ Wk,
    const float* __restrict__ Wv,
    unsigned short* __restrict__ qkv16,
    unsigned short* __restrict__ v_img)
{
    const int ptile = blockIdx.x;   // 0..63
    const int b     = blockIdx.y;
    const int m     = blockIdx.z;
    const float* Wm = (m == 0) ? Wq : ((m == 1) ? Wk : Wv);
    const float* xb = x + (size_t)b * C_ * HW_;
    unsigned short* y = qkv16 + ((size_t)(m * B_ + b)) * HW_ * C_;
    const int p0  = ptile * 64;
    const int tid = threadIdx.x;

    __shared__ unsigned short wls[128 * CPAD];
    __shared__ unsigned short xls[64 * CPAD];

    // ---- border zeroing slice of v_img (disjoint from interior writes) ----
    {
        const int sid = (m * B_ + b) * 64 + ptile;            // 0..767
        const long tot = 4L * 128 * 944;                      // 483328 cells
        long e = (long)sid * 630 + tid;
        const long eend = min((long)(sid + 1) * 630, tot);
        for (; e < eend; e += 256) {
            const int bb  = (int)(e / (128L * 944));
            const int rem = (int)(e - (long)bb * (128L * 944));
            const int c   = rem / 944;
            const int e2  = rem - c * 944;
            int yy, xx;
            if (e2 < 432) { const int k = e2 / 72; yy = (k < 3) ? k : 64 + k; xx = e2 - k * 72; }
            else { const int e3 = e2 - 432; yy = 3 + (e3 >> 3); const int k = e3 & 7; xx = (k < 3) ? k : 64 + k; }
            v_img[(((size_t)bb * 128 + c) * IROWS + yy) * IPITCH + xx] = 0;
        }
    }

    // stage W (cvt in-block)
    #pragma unroll
    for (int it = 0; it < 16; ++it) {
        const int idx = tid + it * 256;
        const int o   = idx >> 5;
        const int c4  = (idx & 31) * 4;
        const float4 w4 = *(const float4*)(Wm + (size_t)o * C_ + c4);
        ushort4 hh;
        hh.x = f2h(w4.x); hh.y = f2h(w4.y); hh.z = f2h(w4.z); hh.w = f2h(w4.w);
        *(ushort4*)(&wls[o * CPAD + c4]) = hh;
    }
    // stage X^T
    #pragma unroll
    for (int it = 0; it < 2; ++it) {
        const int idx = tid + it * 256;
        const int pq  = (idx & 15) * 4;
        const int cq  = (idx >> 4) * 4;
        const float* xp = xb + (size_t)cq * HW_ + p0 + pq;
        const float4 r0 = *(const float4*)(xp);
        const float4 r1 = *(const float4*)(xp + HW_);
        const float4 r2 = *(const float4*)(xp + 2 * HW_);
        const float4 r3 = *(const float4*)(xp + 3 * HW_);
        ushort4 hh;
        hh.x = f2h(r0.x); hh.y = f2h(r1.x); hh.z = f2h(r2.x); hh.w = f2h(r3.x);
        *(ushort4*)(&xls[(pq + 0) * CPAD + cq]) = hh;
        hh.x = f2h(r0.y); hh.y = f2h(r1.y); hh.z = f2h(r2.y); hh.w = f2h(r3.y);
        *(ushort4*)(&xls[(pq + 1) * CPAD + cq]) = hh;
        hh.x = f2h(r0.z); hh.y = f2h(r1.z); hh.z = f2h(r2.z); hh.w = f2h(r3.z);
        *(ushort4*)(&xls[(pq + 2) * CPAD + cq]) = hh;
        hh.x = f2h(r0.w); hh.y = f2h(r1.w); hh.z = f2h(r2.w); hh.w = f2h(r3.w);
        *(ushort4*)(&xls[(pq + 3) * CPAD + cq]) = hh;
    }
    __syncthreads();

    const int wv   = tid >> 6;
    const int lane = tid & 63;
    const int row  = lane & 15;
    const int kq   = lane >> 4;

    f32x4 acc[8];
    #pragma unroll
    for (int ot = 0; ot < 8; ++ot) acc[ot] = (f32x4){0.f, 0.f, 0.f, 0.f};

    #pragma unroll
    for (int ks = 0; ks < 4; ++ks) {
        const int cb = ks * 32 + kq * 8;
        const f16x8 bfrag = *(const f16x8*)(&xls[(wv * 16 + row) * CPAD + cb]);
        #pragma unroll
        for (int ot = 0; ot < 8; ++ot) {
            const f16x8 afrag = *(const f16x8*)(&wls[(ot * 16 + row) * CPAD + cb]);
            acc[ot] = __builtin_amdgcn_mfma_f32_16x16x32_f16(afrag, bfrag, acc[ot], 0, 0, 0);
        }
    }

    // D: lane holds D[o = ot*16 + kq*4 + reg][p = p0 + wv*16 + row]
    const int p = p0 + wv * 16 + row;
    if (m < 2) {
        #pragma unroll
        for (int ot = 0; ot < 8; ++ot) {
            ushort4 hh;
            hh.x = f2h(acc[ot][0]); hh.y = f2h(acc[ot][1]);
            hh.z = f2h(acc[ot][2]); hh.w = f2h(acc[ot][3]);
            *(ushort4*)(y + ((size_t)ot * HW_ + p) * CPG_ + kq * 4) = hh;
        }
    } else {
        const int iy = (p >> 6) + 3, ix = (p & 63) + 3;
        #pragma unroll
        for (int ot = 0; ot < 8; ++ot)
            #pragma unroll
            for (int r = 0; r < 4; ++r) {
                const int o = ot * 16 + kq * 4 + r;
                v_img[(((size_t)b * 128 + o) * IROWS + iy) * IPITCH + ix] = f2h(acc[ot][r]);
            }
    }
}

// ---------------------------------------------------------------------------
// Kernel B: MFMA flash-style grouped 7x7 local attention.
// Per (ph,i): S^T = mfma(K,Q) [2x 16x16x16], online softmax per lane
// (lane&15 = pixel col; 8 w'-slots in regs), PV = 2x mfma(V^T, P) -> C[c,pw].
// grid: (16 tiles, G, B), block 256 (4 waves; wave wv owns ph = 4wv..4wv+3).
// ---------------------------------------------------------------------------
__global__ __launch_bounds__(256) void attn_mfma(
    const unsigned short* __restrict__ qkv16,
    const unsigned short* __restrict__ v_img,
    const float* __restrict__ rel_h,   // [64][7]
    const float* __restrict__ rel_w,   // [64][7]
    float* __restrict__ out)           // [B][128][64][64]
{
    const int tile = blockIdx.x;
    const int g    = blockIdx.y;
    const int b    = blockIdx.z;
    const int h0   = (tile >> 2) * TS;
    const int w0   = (tile & 3) * TS;
    const int c0   = g * CPG_;

    __shared__ unsigned short kls[HALOY * 32 * KWP];   // [y][w' 0..31][ch pitch24]
    __shared__ unsigned short vls[HALOY * 16 * VWP];   // [y][c][w' pitch40]
    __shared__ unsigned short rpls[16 * 16];           // [j][c] f16 rel weights

    const size_t gplane = (size_t)HW_ * CPG_;
    const size_t mplane = (size_t)B_ * G_ * gplane;
    const unsigned short* qb = qkv16          + ((size_t)b * G_ + g) * gplane;
    const unsigned short* kb = qkv16 + mplane + ((size_t)b * G_ + g) * gplane;
    const unsigned short* vi = v_img + ((size_t)b * C_ + c0) * (IROWS * IPITCH);

    const int tid  = threadIdx.x;
    const bool useH = (g < 4);
    const float* rp = useH ? (rel_h + c0 * KW_) : (rel_w + (c0 - 64) * KW_);

    // rel weight table: rpls[j][c] = rp[c][j], zero rows j>=7
    {
        const int j = tid >> 4, c = tid & 15;
        rpls[j * 16 + c] = (j < KW_) ? f2h(rp[c * KW_ + j]) : (unsigned short)0;
    }
    // kls: halo K pixels (y 0..21, w' 0..21), zero OOB; w' 22..31 left garbage (masked)
    #pragma unroll
    for (int it = 0; it < 4; ++it) {
        const int idx = tid + it * 256;
        if (idx < 484 * 2) {
            const int lp = idx >> 1, hf = idx & 1;
            const int yy = lp / HALOY, ww = lp % HALOY;
            const int ty = h0 + yy - PAD_, tx = w0 + ww - PAD_;
            f16x8 val = (f16x8)(_Float16)0.f;
            if ((unsigned)ty < (unsigned)H_ && (unsigned)tx < (unsigned)W_)
                val = *(const f16x8*)(kb + (size_t)(ty * W_ + tx) * CPG_ + hf * 8);
            *(f16x8*)(&kls[(yy * 32 + ww) * KWP + hf * 8]) = val;
        }
    }
    // vls: V^T rows from padded image: w' 0..23 data, 24..31 zero
    #pragma unroll
    for (int it = 0; it < 6; ++it) {
        const int idx = tid + it * 256;
        if (idx < 352 * 4) {
            const int pq = idx >> 2, q4 = idx & 3;
            const int yy = pq >> 4, cc = pq & 15;
            f16x8 val = (f16x8)(_Float16)0.f;
            if (q4 < 3)
                val = *(const f16x8*)(vi + ((size_t)cc * IROWS + (h0 + yy)) * IPITCH + w0 + 8 * q4);
            *(f16x8*)(&vls[(yy * 16 + cc) * VWP + 8 * q4]) = val;
        }
    }
    __syncthreads();

    const int lane = tid & 63, wv = tid >> 6;
    const int l15 = lane & 15, wq = lane >> 4;

    // per-slot validity (j = w' - pw; loop-invariant per lane)
    unsigned msk[8]; float nmk[8];
    #pragma unroll
    for (int r = 0; r < 4; ++r) {
        const int jlo = 4 * wq + r - l15;
        const int jhi = jlo + 16;
        msk[r]     = ((unsigned)jlo <= 6u) ? 0xFFFFFFFFu : 0u;
        msk[4 + r] = ((unsigned)jhi <= 6u) ? 0xFFFFFFFFu : 0u;
        nmk[r]     = msk[r]     ? 0.f : -1e30f;
        nmk[4 + r] = msk[4 + r] ? 0.f : -1e30f;
    }

    const f16x4 rfrag = *(const f16x4*)(&rpls[l15 * 16 + 4 * wq]);
    float* obase = out + ((size_t)b * C_ + c0) * HW_;

    for (int t = 0; t < 4; ++t) {
        const int ph  = wv * 4 + t;
        const int pix = (h0 + ph) * W_ + (w0 + l15);
        const f16x4 qf = *(const f16x4*)(qb + (size_t)pix * CPG_ + 4 * wq);

        // per-pixel rel vector via mfma: D[j, pw]
        const f32x4 rd = __builtin_amdgcn_mfma_f32_16x16x16f16(
            rfrag, qf, (f32x4){0.f, 0.f, 0.f, 0.f}, 0, 0, 0);
        float rl[KW_];
        #pragma unroll
        for (int j = 0; j < KW_; ++j)
            rl[j] = __shfl(rd[j & 3], l15 + 16 * (j >> 2), 64);

        float addW[8];
        if (!useH) {
            #pragma unroll
            for (int r = 0; r < 8; ++r) {
                const int j = 4 * wq + (r & 3) - l15 + ((r & 4) ? 16 : 0);
                float v = -1e30f;
                #pragma unroll
                for (int jj = 0; jj < KW_; ++jj) v = (j == jj) ? rl[jj] : v;
                addW[r] = v;
            }
        }

        f32x4 Cacc = {0.f, 0.f, 0.f, 0.f};
        float m = -1e30f, lsum = 0.f;

        #pragma unroll
        for (int i = 0; i < KW_; ++i) {
            const int yy = ph + i;
            const int kbase = yy * 32 * KWP;
            const f16x4 klo = *(const f16x4*)(&kls[kbase + l15 * KWP + 4 * wq]);
            const f16x4 khi = *(const f16x4*)(&kls[kbase + (16 + l15) * KWP + 4 * wq]);
            const f32x4 S1 = __builtin_amdgcn_mfma_f32_16x16x16f16(
                klo, qf, (f32x4){0.f, 0.f, 0.f, 0.f}, 0, 0, 0);
            const f32x4 S2 = __builtin_amdgcn_mfma_f32_16x16x16f16(
                khi, qf, (f32x4){0.f, 0.f, 0.f, 0.f}, 0, 0, 0);

            float sp[8];
            #pragma unroll
            for (int r = 0; r < 8; ++r) {
                const float s = (r < 4) ? S1[r] : S2[r - 4];
                sp[r] = useH ? (andf(s + rl[i], msk[r]) + nmk[r])
                             : (andf(s, msk[r]) + addW[r]);
            }
            float tm = sp[0];
            #pragma unroll
            for (int r = 1; r < 8; ++r) tm = fmaxf(tm, sp[r]);
            tm = fmaxf(tm, __shfl_xor(tm, 16, 64));
            tm = fmaxf(tm, __shfl_xor(tm, 32, 64));
            const float mnew  = fmaxf(m, tm);
            const float alpha = __expf(m - mnew);
            m = mnew; lsum *= alpha;
            #pragma unroll
            for (int r = 0; r < 4; ++r) Cacc[r] *= alpha;

            float pv[8];
            #pragma unroll
            for (int r = 0; r < 8; ++r) { pv[r] = __expf(sp[r] - mnew); lsum += pv[r]; }
            const f16x4 plo = {(_Float16)pv[0], (_Float16)pv[1], (_Float16)pv[2], (_Float16)pv[3]};
            const f16x4 phi = {(_Float16)pv[4], (_Float16)pv[5], (_Float16)pv[6], (_Float16)pv[7]};

            const int vbase = (yy * 16 + l15) * VWP;
            const f16x4 vlo = *(const f16x4*)(&vls[vbase + 4 * wq]);
            const f16x4 vhi = *(const f16x4*)(&vls[vbase + 16 + 4 * wq]);
            Cacc = __builtin_amdgcn_mfma_f32_16x16x16f16(vlo, plo, Cacc, 0, 0, 0);
            Cacc = __builtin_amdgcn_mfma_f32_16x16x16f16(vhi, phi, Cacc, 0, 0, 0);
        }

        float l2 = lsum + __shfl_xor(lsum, 16, 64);
        l2 = l2 + __shfl_xor(l2, 32, 64);
        const float rden = 1.f / l2;
        #pragma unroll
        for (int r = 0; r < 4; ++r)
            obase[(size_t)(4 * wq + r) * HW_ + pix] = Cacc[r] * rden;
    }
}

// ---------------------------------------------------------------------------
extern "C" void kernel_launch(void* const* d_in, const int* in_sizes, int n_in,
                              void* d_out, int out_size, void* d_ws, size_t ws_size,
                              hipStream_t stream) {
    const float* x     = (const float*)d_in[0];
    const float* Wq    = (const float*)d_in[1];
    const float* Wk    = (const float*)d_in[2];
    const float* Wv    = (const float*)d_in[3];
    const float* rel_h = (const float*)d_in[4];
    const float* rel_w = (const float*)d_in[5];
    unsigned short* ws    = (unsigned short*)d_ws;
    unsigned short* qkv   = ws;                                  // q,k pixel-major (12 MB region)
    unsigned short* v_img = ws + (size_t)3 * B_ * HW_ * C_;      // [4][128][72][80] f16
    float* out = (float*)d_out;

    dim3 gA(HW_ / 64, B_, 3);
    proj_mfma<<<gA, 256, 0, stream>>>(x, Wq, Wk, Wv, qkv, v_img);

    dim3 gB(16, G_, B_);
    attn_mfma<<<gB, 256, 0, stream>>>(qkv, v_img, rel_h, rel_w, out);
}

// Round 13
// 37.063 us; speedup vs baseline: 1.2437x; 1.1004x over previous
//
#include <hip/hip_runtime.h>
#include <hip/hip_bf16.h>

#define B_   4
#define C_   128
#define H_   64
#define W_   64
#define HW_  4096
#define KW_  7
#define PAD_ 3
#define G_   8
#define CPG_ 16

#define CPAD 136   // f16 elems per LDS row in proj; row stride 272 B

// attn geometry
#define TS     16
#define HALOY  22
#define KWP    24      // kls per-(y,w') pitch (ushorts)
#define VWP    40      // vls per-(y,c) pitch (ushorts)

typedef _Float16 f16x4 __attribute__((ext_vector_type(4)));
typedef _Float16 f16x8 __attribute__((ext_vector_type(8)));
typedef float    f32x4 __attribute__((ext_vector_type(4)));

static __device__ __forceinline__ unsigned short f2h(float f) {
    _Float16 h = (_Float16)f;
    union { _Float16 h; unsigned short u; } cv; cv.h = h;
    return cv.u;
}
static __device__ __forceinline__ float andf(float x, unsigned m) {
    return __uint_as_float(__float_as_uint(x) & m);
}

// ---------------------------------------------------------------------------
// Kernel A: fp16-MFMA 1x1 conv projections (VERBATIM round-10, the best).
// Output: fp16, GROUP-PLANAR qkv16[m][b][g][pix][16] (pixel stride 32 B).
// grid: (64 p-tiles, B, 3), block 256 (4 waves).
// ---------------------------------------------------------------------------
__global__ __launch_bounds__(256) void proj_mfma(
    const float* __restrict__ x,
    const float* __restrict__ Wq,
    const float* __restrict__ Wk,
    const float* __restrict__ Wv,
    unsigned short* __restrict__ qkv16)
{
    const int ptile = blockIdx.x;   // 0..63
    const int b     = blockIdx.y;
    const int m     = blockIdx.z;
    const float* Wm = (m == 0) ? Wq : ((m == 1) ? Wk : Wv);
    const float* xb = x + (size_t)b * C_ * HW_;
    unsigned short* y = qkv16 + ((size_t)(m * B_ + b)) * HW_ * C_;
    const int p0  = ptile * 64;
    const int tid = threadIdx.x;

    __shared__ unsigned short wls[128 * CPAD];
    __shared__ unsigned short xls[64 * CPAD];

    #pragma unroll
    for (int it = 0; it < 16; ++it) {
        const int idx = tid + it * 256;
        const int o   = idx >> 5;
        const int c4  = (idx & 31) * 4;
        const float4 w4 = *(const float4*)(Wm + (size_t)o * C_ + c4);
        ushort4 hh;
        hh.x = f2h(w4.x); hh.y = f2h(w4.y); hh.z = f2h(w4.z); hh.w = f2h(w4.w);
        *(ushort4*)(&wls[o * CPAD + c4]) = hh;
    }
    #pragma unroll
    for (int it = 0; it < 2; ++it) {
        const int idx = tid + it * 256;
        const int pq  = (idx & 15) * 4;
        const int cq  = (idx >> 4) * 4;
        const float* xp = xb + (size_t)cq * HW_ + p0 + pq;
        const float4 r0 = *(const float4*)(xp);
        const float4 r1 = *(const float4*)(xp + HW_);
        const float4 r2 = *(const float4*)(xp + 2 * HW_);
        const float4 r3 = *(const float4*)(xp + 3 * HW_);
        ushort4 hh;
        hh.x = f2h(r0.x); hh.y = f2h(r1.x); hh.z = f2h(r2.x); hh.w = f2h(r3.x);
        *(ushort4*)(&xls[(pq + 0) * CPAD + cq]) = hh;
        hh.x = f2h(r0.y); hh.y = f2h(r1.y); hh.z = f2h(r2.y); hh.w = f2h(r3.y);
        *(ushort4*)(&xls[(pq + 1) * CPAD + cq]) = hh;
        hh.x = f2h(r0.z); hh.y = f2h(r1.z); hh.z = f2h(r2.z); hh.w = f2h(r3.z);
        *(ushort4*)(&xls[(pq + 2) * CPAD + cq]) = hh;
        hh.x = f2h(r0.w); hh.y = f2h(r1.w); hh.z = f2h(r2.w); hh.w = f2h(r3.w);
        *(ushort4*)(&xls[(pq + 3) * CPAD + cq]) = hh;
    }
    __syncthreads();

    const int wv   = tid >> 6;
    const int lane = tid & 63;
    const int row  = lane & 15;
    const int kq   = lane >> 4;

    f32x4 acc[8];
    #pragma unroll
    for (int ot = 0; ot < 8; ++ot) acc[ot] = (f32x4){0.f, 0.f, 0.f, 0.f};

    #pragma unroll
    for (int ks = 0; ks < 4; ++ks) {
        const int cb = ks * 32 + kq * 8;
        const f16x8 bfrag = *(const f16x8*)(&xls[(wv * 16 + row) * CPAD + cb]);
        #pragma unroll
        for (int ot = 0; ot < 8; ++ot) {
            const f16x8 afrag = *(const f16x8*)(&wls[(ot * 16 + row) * CPAD + cb]);
            acc[ot] = __builtin_amdgcn_mfma_f32_16x16x32_f16(afrag, bfrag, acc[ot], 0, 0, 0);
        }
    }

    const int p = p0 + wv * 16 + row;
    #pragma unroll
    for (int ot = 0; ot < 8; ++ot) {
        ushort4 hh;
        hh.x = f2h(acc[ot][0]); hh.y = f2h(acc[ot][1]);
        hh.z = f2h(acc[ot][2]); hh.w = f2h(acc[ot][3]);
        *(ushort4*)(y + ((size_t)ot * HW_ + p) * CPG_ + kq * 4) = hh;
    }
}

// ---------------------------------------------------------------------------
// Kernel B: MFMA grouped 7x7 local attention, DEFERRED softmax.
// Per (wave, ph-row): 14 QK MFMAs -> 56 score slots in regs -> one
// max/exp/sum pass (2+2 shfl total) -> 14 PV MFMAs. V transposed to
// channel-major vls[y][c][w'] inside the kernel (scalar ds_write_b16).
// grid: (16 tiles, G, B), block 256 (4 waves; wave wv owns ph = 4wv..4wv+3).
// ---------------------------------------------------------------------------
__global__ __launch_bounds__(256) void attn_mfma(
    const unsigned short* __restrict__ qkv16,
    const float* __restrict__ rel_h,   // [64][7]
    const float* __restrict__ rel_w,   // [64][7]
    float* __restrict__ out)           // [B][128][64][64]
{
    const int tile = blockIdx.x;
    const int g    = blockIdx.y;
    const int b    = blockIdx.z;
    const int h0   = (tile >> 2) * TS;
    const int w0   = (tile & 3) * TS;
    const int c0   = g * CPG_;

    __shared__ unsigned short kls[HALOY * 32 * KWP];   // [y][w'][ch]; w'22..31 garbage (masked)
    __shared__ unsigned short vls[HALOY * 16 * VWP];   // [y][c][w']; w'22..31 zeroed
    __shared__ unsigned short rpls[16 * 16];           // [j][c] f16 rel weights

    const size_t gplane = (size_t)HW_ * CPG_;
    const size_t mplane = (size_t)B_ * G_ * gplane;
    const unsigned short* qb = qkv16              + ((size_t)b * G_ + g) * gplane;
    const unsigned short* kb = qkv16 + mplane     + ((size_t)b * G_ + g) * gplane;
    const unsigned short* vb = qkv16 + 2 * mplane + ((size_t)b * G_ + g) * gplane;

    const int tid  = threadIdx.x;
    const bool useH = (g < 4);
    const float* rp = useH ? (rel_h + c0 * KW_) : (rel_w + (c0 - 64) * KW_);

    // rel weight table: rpls[j][c] = rp[c][j], zero rows j>=7
    {
        const int j = tid >> 4, c = tid & 15;
        rpls[j * 16 + c] = (j < KW_) ? f2h(rp[c * KW_ + j]) : (unsigned short)0;
    }
    // kls: K halo pixel-major (y 0..21, w' 0..21), zero OOB
    #pragma unroll
    for (int it = 0; it < 4; ++it) {
        const int idx = tid + it * 256;
        if (idx < 484 * 2) {
            const int lp = idx >> 1, hf = idx & 1;
            const int yy = lp / HALOY, ww = lp - yy * HALOY;
            const int ty = h0 + yy - PAD_, tx = w0 + ww - PAD_;
            f16x8 val = (f16x8)(_Float16)0.f;
            if ((unsigned)ty < (unsigned)H_ && (unsigned)tx < (unsigned)W_)
                val = *(const f16x8*)(kb + (size_t)(ty * W_ + tx) * CPG_ + hf * 8);
            *(f16x8*)(&kls[(yy * 32 + ww) * KWP + hf * 8]) = val;
        }
    }
    // vls: zero tail w' 22..31 for all (y,c) rows
    #pragma unroll
    for (int it = 0; it < 2; ++it) {
        const int idx = tid + it * 256;
        if (idx < HALOY * 16) {
            unsigned short* p = &vls[idx * VWP];
            *(unsigned int*)(p + 22) = 0u;
            *(f16x8*)(p + 24) = (f16x8)(_Float16)0.f;
        }
    }
    // vls: V halo transposed to channel-major via scalar ds writes
    #pragma unroll
    for (int it = 0; it < 4; ++it) {
        const int idx = tid + it * 256;
        if (idx < 484 * 2) {
            const int lp = idx >> 1, hf = idx & 1;
            const int yy = lp / HALOY, ww = lp - yy * HALOY;
            const int ty = h0 + yy - PAD_, tx = w0 + ww - PAD_;
            f16x8 val = (f16x8)(_Float16)0.f;
            if ((unsigned)ty < (unsigned)H_ && (unsigned)tx < (unsigned)W_)
                val = *(const f16x8*)(vb + (size_t)(ty * W_ + tx) * CPG_ + hf * 8);
            union { f16x8 v; unsigned short u[8]; } cv; cv.v = val;
            unsigned short* dst = &vls[(yy * 16 + hf * 8) * VWP + ww];
            #pragma unroll
            for (int c = 0; c < 8; ++c) dst[c * VWP] = cv.u[c];
        }
    }
    __syncthreads();

    const int lane = tid & 63, wv = tid >> 6;
    const int l15 = lane & 15, wq = lane >> 4;

    // per-slot validity (j = w' - pw; loop-invariant per lane)
    unsigned msk[8]; float nmk[8];
    #pragma unroll
    for (int r = 0; r < 4; ++r) {
        const int jlo = 4 * wq + r - l15;
        const int jhi = jlo + 16;
        msk[r]     = ((unsigned)jlo <= 6u) ? 0xFFFFFFFFu : 0u;
        msk[4 + r] = ((unsigned)jhi <= 6u) ? 0xFFFFFFFFu : 0u;
        nmk[r]     = msk[r]     ? 0.f : -1e30f;
        nmk[4 + r] = msk[4 + r] ? 0.f : -1e30f;
    }

    const f16x4 rfrag = *(const f16x4*)(&rpls[l15 * 16 + 4 * wq]);
    float* obase = out + ((size_t)b * C_ + c0) * HW_;

    for (int t = 0; t < 4; ++t) {
        const int ph  = wv * 4 + t;
        const int pix = (h0 + ph) * W_ + (w0 + l15);
        const f16x4 qf = *(const f16x4*)(qb + (size_t)pix * CPG_ + 4 * wq);

        // per-pixel rel vector via mfma: D[j, pw]
        const f32x4 rd = __builtin_amdgcn_mfma_f32_16x16x16f16(
            rfrag, qf, (f32x4){0.f, 0.f, 0.f, 0.f}, 0, 0, 0);
        float rl[KW_];
        #pragma unroll
        for (int j = 0; j < KW_; ++j)
            rl[j] = __shfl(rd[j & 3], l15 + 16 * (j >> 2), 64);

        float addW[8];
        if (!useH) {
            #pragma unroll
            for (int r = 0; r < 8; ++r) {
                const int j = 4 * wq + (r & 3) - l15 + ((r & 4) ? 16 : 0);
                float v = -1e30f;
                #pragma unroll
                for (int jj = 0; jj < KW_; ++jj) v = (j == jj) ? rl[jj] : v;
                addW[r] = v;
            }
        }

        // ---- all 56 scores via 14 MFMAs ----
        float s[KW_][8];
        #pragma unroll
        for (int i = 0; i < KW_; ++i) {
            const int kbase = (ph + i) * 32 * KWP;
            const f16x4 klo = *(const f16x4*)(&kls[kbase + l15 * KWP + 4 * wq]);
            const f16x4 khi = *(const f16x4*)(&kls[kbase + (16 + l15) * KWP + 4 * wq]);
            const f32x4 S1 = __builtin_amdgcn_mfma_f32_16x16x16f16(
                klo, qf, (f32x4){0.f, 0.f, 0.f, 0.f}, 0, 0, 0);
            const f32x4 S2 = __builtin_amdgcn_mfma_f32_16x16x16f16(
                khi, qf, (f32x4){0.f, 0.f, 0.f, 0.f}, 0, 0, 0);
            #pragma unroll
            for (int r = 0; r < 8; ++r) {
                const float raw = (r < 4) ? S1[r] : S2[r - 4];
                s[i][r] = useH ? (andf(raw + rl[i], msk[r]) + nmk[r])
                               : (andf(raw, msk[r]) + addW[r]);
            }
        }

        // ---- deferred softmax: one max, one exp, one sum ----
        float m = s[0][0];
        #pragma unroll
        for (int i = 0; i < KW_; ++i)
            #pragma unroll
            for (int r = 0; r < 8; ++r) m = fmaxf(m, s[i][r]);
        m = fmaxf(m, __shfl_xor(m, 16, 64));
        m = fmaxf(m, __shfl_xor(m, 32, 64));

        float lsum = 0.f;
        #pragma unroll
        for (int i = 0; i < KW_; ++i)
            #pragma unroll
            for (int r = 0; r < 8; ++r) { s[i][r] = __expf(s[i][r] - m); lsum += s[i][r]; }

        // ---- PV: 14 MFMAs ----
        f32x4 Cacc = {0.f, 0.f, 0.f, 0.f};
        #pragma unroll
        for (int i = 0; i < KW_; ++i) {
            const f16x4 plo = {(_Float16)s[i][0], (_Float16)s[i][1],
                               (_Float16)s[i][2], (_Float16)s[i][3]};
            const f16x4 phi = {(_Float16)s[i][4], (_Float16)s[i][5],
                               (_Float16)s[i][6], (_Float16)s[i][7]};
            const int vbase = (ph + i) * 16 * VWP + l15 * VWP;
            const f16x4 vlo = *(const f16x4*)(&vls[vbase + 4 * wq]);
            const f16x4 vhi = *(const f16x4*)(&vls[vbase + 16 + 4 * wq]);
            Cacc = __builtin_amdgcn_mfma_f32_16x16x16f16(vlo, plo, Cacc, 0, 0, 0);
            Cacc = __builtin_amdgcn_mfma_f32_16x16x16f16(vhi, phi, Cacc, 0, 0, 0);
        }

        float l2 = lsum + __shfl_xor(lsum, 16, 64);
        l2 = l2 + __shfl_xor(l2, 32, 64);
        const float rden = 1.f / l2;
        #pragma unroll
        for (int r = 0; r < 4; ++r)
            obase[(size_t)(4 * wq + r) * HW_ + pix] = Cacc[r] * rden;
    }
}

// ---------------------------------------------------------------------------
extern "C" void kernel_launch(void* const* d_in, const int* in_sizes, int n_in,
                              void* d_out, int out_size, void* d_ws, size_t ws_size,
                              hipStream_t stream) {
    const float* x     = (const float*)d_in[0];
    const float* Wq    = (const float*)d_in[1];
    const float* Wk    = (const float*)d_in[2];
    const float* Wv    = (const float*)d_in[3];
    const float* rel_h = (const float*)d_in[4];
    const float* rel_w = (const float*)d_in[5];
    unsigned short* ws = (unsigned short*)d_ws;  // fp16 qkv [3][B][G][4096][16] = 12 MB
    float* out = (float*)d_out;

    dim3 gA(HW_ / 64, B_, 3);
    proj_mfma<<<gA, 256, 0, stream>>>(x, Wq, Wk, Wv, ws);

    dim3 gB(16, G_, B_);
    attn_mfma<<<gB, 256, 0, stream>>>(ws, rel_h, rel_w, out);
}

// Round 14
// 31.279 us; speedup vs baseline: 1.4736x; 1.1849x over previous
//
#include <hip/hip_runtime.h>
#include <hip/hip_bf16.h>

#define B_   4
#define C_   128
#define H_   64
#define W_   64
#define HW_  4096
#define KW_  7
#define PAD_ 3
#define G_   8
#define CPG_ 16

#define CPAD 136   // f16 elems per LDS row in proj; row stride 272 B

// attn LDS geometry (round-6/10 proven)
#define TS    16
#define HALO  22
#define NHP   (HALO*HALO)
#define LP    24          // ushorts per pixel (48 B): balanced banks, 16B-aligned

typedef _Float16 f16x8 __attribute__((ext_vector_type(8)));
typedef _Float16 f16x2 __attribute__((ext_vector_type(2)));
typedef _Float16 h2    __attribute__((ext_vector_type(2)));
typedef float    f32x4 __attribute__((ext_vector_type(4)));

static __device__ __forceinline__ unsigned short f2h(float f) {
    _Float16 h = (_Float16)f;
    union { _Float16 h; unsigned short u; } cv; cv.h = h;
    return cv.u;
}

#if defined(__has_builtin)
#if __has_builtin(__builtin_amdgcn_fdot2)
#define HAVE_FDOT2 1
#endif
#endif

// ---------------------------------------------------------------------------
// Kernel A: fp16-MFMA 1x1 conv projections, O-HALF SPLIT for occupancy.
// Each block: 64 output channels x 64 pixels. LDS 34.8 KB -> 4 blocks/CU.
// grid: (64 p-tiles, B, 6 = 3 matrices x 2 o-halves), block 256 (4 waves).
// Output: fp16, GROUP-PLANAR qkv16[m][b][g][pix][16] (pixel stride 32 B).
// ---------------------------------------------------------------------------
__global__ __launch_bounds__(256) void proj_mfma(
    const float* __restrict__ x,
    const float* __restrict__ Wq,
    const float* __restrict__ Wk,
    const float* __restrict__ Wv,
    unsigned short* __restrict__ qkv16)
{
    const int ptile = blockIdx.x;        // 0..63
    const int b     = blockIdx.y;
    const int mz    = blockIdx.z;        // 0..5
    const int m     = mz >> 1;
    const int oh    = mz & 1;            // o-half: channels oh*64 .. oh*64+63
    const float* Wm = (m == 0) ? Wq : ((m == 1) ? Wk : Wv);
    const float* xb = x + (size_t)b * C_ * HW_;
    unsigned short* y = qkv16 + ((size_t)(m * B_ + b)) * HW_ * C_;
    const int p0  = ptile * 64;
    const int tid = threadIdx.x;

    __shared__ unsigned short wls[64 * CPAD];   // [o-local][c] f16
    __shared__ unsigned short xls[64 * CPAD];   // [p][c] f16 (transposed X)

    // stage W half: 64 o x 128 c (8 iters)
    #pragma unroll
    for (int it = 0; it < 8; ++it) {
        const int idx = tid + it * 256;
        const int o   = idx >> 5;            // 0..63 local row
        const int c4  = (idx & 31) * 4;
        const float4 w4 = *(const float4*)(Wm + (size_t)(oh * 64 + o) * C_ + c4);
        ushort4 hh;
        hh.x = f2h(w4.x); hh.y = f2h(w4.y); hh.z = f2h(w4.z); hh.w = f2h(w4.w);
        *(ushort4*)(&wls[o * CPAD + c4]) = hh;
    }
    // stage X^T: 4c x 4p micro-transpose blocks (2 iters)
    #pragma unroll
    for (int it = 0; it < 2; ++it) {
        const int idx = tid + it * 256;
        const int pq  = (idx & 15) * 4;
        const int cq  = (idx >> 4) * 4;
        const float* xp = xb + (size_t)cq * HW_ + p0 + pq;
        const float4 r0 = *(const float4*)(xp);
        const float4 r1 = *(const float4*)(xp + HW_);
        const float4 r2 = *(const float4*)(xp + 2 * HW_);
        const float4 r3 = *(const float4*)(xp + 3 * HW_);
        ushort4 hh;
        hh.x = f2h(r0.x); hh.y = f2h(r1.x); hh.z = f2h(r2.x); hh.w = f2h(r3.x);
        *(ushort4*)(&xls[(pq + 0) * CPAD + cq]) = hh;
        hh.x = f2h(r0.y); hh.y = f2h(r1.y); hh.z = f2h(r2.y); hh.w = f2h(r3.y);
        *(ushort4*)(&xls[(pq + 1) * CPAD + cq]) = hh;
        hh.x = f2h(r0.z); hh.y = f2h(r1.z); hh.z = f2h(r2.z); hh.w = f2h(r3.z);
        *(ushort4*)(&xls[(pq + 2) * CPAD + cq]) = hh;
        hh.x = f2h(r0.w); hh.y = f2h(r1.w); hh.z = f2h(r2.w); hh.w = f2h(r3.w);
        *(ushort4*)(&xls[(pq + 3) * CPAD + cq]) = hh;
    }
    __syncthreads();

    const int wv   = tid >> 6;     // wave id: owns 16 pixels
    const int lane = tid & 63;
    const int row  = lane & 15;
    const int kq   = lane >> 4;

    f32x4 acc[4];
    #pragma unroll
    for (int ot = 0; ot < 4; ++ot)
        acc[ot] = (f32x4){0.f, 0.f, 0.f, 0.f};

    #pragma unroll
    for (int ks = 0; ks < 4; ++ks) {
        const int cb = ks * 32 + kq * 8;
        const f16x8 bfrag = *(const f16x8*)(&xls[(wv * 16 + row) * CPAD + cb]);
        #pragma unroll
        for (int ot = 0; ot < 4; ++ot) {
            const f16x8 afrag = *(const f16x8*)(&wls[(ot * 16 + row) * CPAD + cb]);
            acc[ot] = __builtin_amdgcn_mfma_f32_16x16x32_f16(afrag, bfrag, acc[ot], 0, 0, 0);
        }
    }

    // D: lane holds D[o-local = ot*16 + kq*4 + reg][p = p0 + wv*16 + row]
    // global group = oh*4 + ot; within-group channel = kq*4 + reg.
    const int p = p0 + wv * 16 + row;
    #pragma unroll
    for (int ot = 0; ot < 4; ++ot) {
        const int got = oh * 4 + ot;
        ushort4 hh;
        hh.x = f2h(acc[ot][0]); hh.y = f2h(acc[ot][1]);
        hh.z = f2h(acc[ot][2]); hh.w = f2h(acc[ot][3]);
        *(ushort4*)(y + ((size_t)got * HW_ + p) * CPG_ + kq * 4) = hh;
    }
}

// ---------------------------------------------------------------------------
// Kernel B: grouped 7x7 local attention (round-10 structure), fdot2 scores,
// PACKED-f16 PV accumulation (v_pk_fma_f16; error suppressed by 1/den).
// grid: (16 tiles, G, B), block 256.
// ---------------------------------------------------------------------------
__global__ __launch_bounds__(256) void attn_kernel(
    const unsigned short* __restrict__ qkv16,
    const float* __restrict__ rel_h,   // [64][7]
    const float* __restrict__ rel_w,   // [64][7]
    float* __restrict__ out)           // [B][128][64][64]
{
    const int tile = blockIdx.x;
    const int g    = blockIdx.y;
    const int b    = blockIdx.z;
    const int h0   = (tile >> 2) * TS;
    const int w0   = (tile & 3) * TS;
    const int c0   = g * CPG_;

    __shared__ unsigned short kvls[2][NHP * LP];

    const size_t gplane = (size_t)HW_ * CPG_;
    const size_t mplane = (size_t)B_ * G_ * gplane;
    const unsigned short* qb = qkv16              + ((size_t)b * G_ + g) * gplane;
    const unsigned short* kb = qkv16 + mplane     + ((size_t)b * G_ + g) * gplane;
    const unsigned short* vb = qkv16 + 2 * mplane + ((size_t)b * G_ + g) * gplane;

    const int tid = threadIdx.x;
    const int pw  = tid & 15;
    const int ph  = tid >> 4;
    const int pix = (h0 + ph) * W_ + (w0 + pw);

    // q fragment first (independent of staging -> overlaps)
    const f16x8 q0 = *(const f16x8*)(qb + (size_t)pix * CPG_);
    const f16x8 q1 = *(const f16x8*)(qb + (size_t)pix * CPG_ + 8);

    // stage K and V halo: 1936 x 16B chunks, coalesced, zero-fill OOB
    #pragma unroll
    for (int it = 0; it < 8; ++it) {
        const int idx = tid + it * 256;
        if (idx < 2 * NHP * 2) {
            const int arr  = (idx >= NHP * 2) ? 1 : 0;
            const int r    = idx - arr * NHP * 2;
            const int lp   = r >> 1;
            const int half = r & 1;
            const int hy   = h0 + lp / HALO - PAD_;
            const int hx   = w0 + lp % HALO - PAD_;
            f16x8 val = (f16x8)(_Float16)0.f;
            if ((unsigned)hy < (unsigned)H_ && (unsigned)hx < (unsigned)W_) {
                const unsigned short* src = (arr ? vb : kb)
                    + (size_t)(hy * W_ + hx) * CPG_ + half * 8;
                val = *(const f16x8*)src;
            }
            *(f16x8*)(&kvls[arr][lp * LP + half * 8]) = val;
        }
    }

    float qv[CPG_];
    #pragma unroll
    for (int c = 0; c < 8; ++c) { qv[c] = (float)q0[c]; qv[8 + c] = (float)q1[c]; }

    // rel score
    const bool useH = (g < 4);
    const float* rp = useH ? (rel_h + c0 * KW_) : (rel_w + (c0 - 64) * KW_);
    float rel[KW_];
    #pragma unroll
    for (int t = 0; t < KW_; ++t) {
        float r = 0.f;
        #pragma unroll
        for (int c = 0; c < CPG_; ++c) r += qv[c] * rp[c * KW_ + t];
        rel[t] = r;
    }

    __syncthreads();

    // scores: all 49 positions
    float s[KW_ * KW_];
    float smax = -1e30f;
    #pragma unroll
    for (int i = 0; i < KW_; ++i) {
        #pragma unroll
        for (int j = 0; j < KW_; ++j) {
            const unsigned short* kp = &kvls[0][((ph + i) * HALO + (pw + j)) * LP];
            const f16x8 k0 = *(const f16x8*)(kp);
            const f16x8 k1 = *(const f16x8*)(kp + 8);
            float sc = useH ? rel[i] : rel[j];
#ifdef HAVE_FDOT2
            #pragma unroll
            for (int t = 0; t < 4; ++t) {
                sc = __builtin_amdgcn_fdot2((h2){q0[2*t], q0[2*t+1]},
                                            (h2){k0[2*t], k0[2*t+1]}, sc, false);
                sc = __builtin_amdgcn_fdot2((h2){q1[2*t], q1[2*t+1]},
                                            (h2){k1[2*t], k1[2*t+1]}, sc, false);
            }
#else
            #pragma unroll
            for (int c = 0; c < 8; ++c)
                sc += qv[c] * (float)k0[c] + qv[8 + c] * (float)k1[c];
#endif
            s[i * KW_ + j] = sc;
            smax = fmaxf(smax, sc);
        }
    }

    // softmax
    float denom = 0.f;
    #pragma unroll
    for (int n = 0; n < KW_ * KW_; ++n) {
        s[n] = __expf(s[n] - smax);
        denom += s[n];
    }
    const float rdenom = 1.f / denom;

    // output = attn . V  -- packed f16x2 accumulation (a_j <= 1, den >= 1:
    // f16 round-off on the unnormalized acc is shrunk by rdenom at the end)
    f16x2 acch[8];
    #pragma unroll
    for (int c = 0; c < 8; ++c) acch[c] = (f16x2){(_Float16)0.f, (_Float16)0.f};

    #pragma unroll
    for (int i = 0; i < KW_; ++i) {
        #pragma unroll
        for (int j = 0; j < KW_; ++j) {
            const _Float16 ah = (_Float16)s[i * KW_ + j];
            const f16x2 av = {ah, ah};
            const unsigned short* vp = &kvls[1][((ph + i) * HALO + (pw + j)) * LP];
            const f16x8 v0 = *(const f16x8*)(vp);
            const f16x8 v1 = *(const f16x8*)(vp + 8);
            #pragma unroll
            for (int c = 0; c < 4; ++c) {
                const f16x2 p0v = {v0[2 * c], v0[2 * c + 1]};
                const f16x2 p1v = {v1[2 * c], v1[2 * c + 1]};
                acch[c]     += av * p0v;
                acch[4 + c] += av * p1v;
            }
        }
    }

    float* ob = out + ((size_t)b * C_ + c0) * HW_;
    #pragma unroll
    for (int c = 0; c < 8; ++c) {
        ob[(size_t)(2 * c)     * HW_ + pix] = (float)acch[c][0] * rdenom;
        ob[(size_t)(2 * c + 1) * HW_ + pix] = (float)acch[c][1] * rdenom;
    }
}

// ---------------------------------------------------------------------------
extern "C" void kernel_launch(void* const* d_in, const int* in_sizes, int n_in,
                              void* d_out, int out_size, void* d_ws, size_t ws_size,
                              hipStream_t stream) {
    const float* x     = (const float*)d_in[0];
    const float* Wq    = (const float*)d_in[1];
    const float* Wk    = (const float*)d_in[2];
    const float* Wv    = (const float*)d_in[3];
    const float* rel_h = (const float*)d_in[4];
    const float* rel_w = (const float*)d_in[5];
    unsigned short* ws = (unsigned short*)d_ws;  // fp16 qkv [3][B][G][4096][16] = 12 MB
    float* out = (float*)d_out;

    dim3 gA(HW_ / 64, B_, 6);
    proj_mfma<<<gA, 256, 0, stream>>>(x, Wq, Wk, Wv, ws);

    dim3 gB(16, G_, B_);
    attn_kernel<<<gB, 256, 0, stream>>>(ws, rel_h, rel_w, out);
}